// Round 9
// baseline (68.678 us; speedup 1.0000x reference)
//
#include <hip/hip_runtime.h>

typedef __bf16 bf16x8 __attribute__((ext_vector_type(8)));
typedef unsigned short u16x8 __attribute__((ext_vector_type(8)));
typedef float f32x4 __attribute__((ext_vector_type(4)));

#define D_DIM 256
// base-2 scale: sv2 = acc * INV_T * log2(e); exp(sv)=2^(sv2)
#define C2 2.88539008f
#define LN2 0.69314718f

__device__ __forceinline__ unsigned short f2bf(float f) {
  union { float f; unsigned u; } x; x.f = f;
  unsigned r = x.u + 0x7FFFu + ((x.u >> 16) & 1u);  // round-to-nearest-even
  return (unsigned short)(r >> 16);
}

// Fragment-native layout L: element (row,k) lives at
//   ((row>>4)*32 + (k>>3))*128 + (row&15)*8 + (k&7)
// so an MFMA a/b fragment (16 rows x 32 k) is 1KB CONTIGUOUS per wave:
// lane offset = 16*lane bytes. Global->VGPR fragment loads coalesce perfectly.

// ---------------- Kernel 1: L2-normalize -> bf16 L-layout R -----------------
__global__ __launch_bounds__(256) void k_normalize(const float* __restrict__ ei,
                                                   const float* __restrict__ ej,
                                                   unsigned short* __restrict__ R,
                                                   unsigned* __restrict__ ticket,
                                                   int B) {
  if (blockIdx.x == 0 && threadIdx.x == 0) *ticket = 0u;  // per-call reset
  const int w = threadIdx.x >> 6, lane = threadIdx.x & 63;
  const int row = blockIdx.x * 16 + w * 4 + (lane >> 4);
  const int kq = lane & 15;  // 16-element k-chunk owned by this lane
  const float* src = (row < B) ? (ei + (size_t)row * D_DIM)
                               : (ej + (size_t)(row - B) * D_DIM);
  const float4* s4 = (const float4*)src + kq * 4;
  float4 v0 = s4[0], v1 = s4[1], v2 = s4[2], v3 = s4[3];
  float ss = v0.x*v0.x + v0.y*v0.y + v0.z*v0.z + v0.w*v0.w
           + v1.x*v1.x + v1.y*v1.y + v1.z*v1.z + v1.w*v1.w
           + v2.x*v2.x + v2.y*v2.y + v2.z*v2.z + v2.w*v2.w
           + v3.x*v3.x + v3.y*v3.y + v3.z*v3.z + v3.w*v3.w;
#pragma unroll
  for (int d = 1; d < 16; d <<= 1) ss += __shfl_xor(ss, d, 64);  // 16-group
  const float s = 1.0f / fmaxf(sqrtf(ss), 1e-12f);
  u16x8 o0, o1;
  o0[0] = f2bf(v0.x*s); o0[1] = f2bf(v0.y*s); o0[2] = f2bf(v0.z*s); o0[3] = f2bf(v0.w*s);
  o0[4] = f2bf(v1.x*s); o0[5] = f2bf(v1.y*s); o0[6] = f2bf(v1.z*s); o0[7] = f2bf(v1.w*s);
  o1[0] = f2bf(v2.x*s); o1[1] = f2bf(v2.y*s); o1[2] = f2bf(v2.z*s); o1[3] = f2bf(v2.w*s);
  o1[4] = f2bf(v3.x*s); o1[5] = f2bf(v3.y*s); o1[6] = f2bf(v3.z*s); o1[7] = f2bf(v3.w*s);
  // chunk = (row>>4)*32 + kq*2 (+1); 16B-unit index = chunk*16 + (row&15)
  const size_t idx0 = ((size_t)(row >> 4) * 32 + kq * 2) * 16 + (row & 15);
  ((u16x8*)R)[idx0] = o0;
  ((u16x8*)R)[idx0 + 16] = o1;
}

// ---------------- Kernel 2: symmetric fused sim GEMM + exp partials ---------
// Upper-triangular 128x128 tiles (bi <= bj). NO LDS, NO barriers: fragments
// load straight from the L-layout (1KB contiguous per wave-load). HAND
// SOFTWARE-PIPELINE: two named fragment sets ping-pong (static indexing,
// rule #20); loads for kt+1 issue before kt's MFMA block, so compiler-
// inserted counted waitcnt overlaps L2 latency with MFMA issue. Each of the
// 4 waves/block is fully independent (no lockstep).
__global__ __launch_bounds__(256) void k_simgemm(const unsigned short* __restrict__ R,
                                                 float* __restrict__ rowPartial,
                                                 float* __restrict__ simTgt,
                                                 int N) {
  const int tid = threadIdx.x;
  const int w = tid >> 6, lane = tid & 63;
  const int wr = w >> 1, wc = w & 1;
  const int half = N >> 1;

  // decode linear block id -> upper-triangular (bi, bj), bi <= bj
  const int T = N / 128;  // 64
  const int t = blockIdx.x;
  int bi = (int)(((float)(2 * T + 1) -
                  sqrtf((float)((2 * T + 1) * (2 * T + 1) - 8 * t))) * 0.5f);
  while (bi > 0 && t < bi * (2 * T - bi + 1) / 2) --bi;
  while (t >= (bi + 1) * (2 * T - bi) / 2) ++bi;
  const int bj = bi + (t - bi * (2 * T - bi + 1) / 2);
  const int brow = bi * 128, bcol = bj * 128;
  const bool offdiag = (bi != bj);

  f32x4 zero4 = {0.f, 0.f, 0.f, 0.f};
  f32x4 acc[4][4];
#pragma unroll
  for (int m = 0; m < 4; ++m)
#pragma unroll
    for (int n = 0; n < 4; ++n) acc[m][n] = zero4;

  const bf16x8* Lf = (const bf16x8*)R;         // 16B-unit view of L layout
  const int arb = (brow >> 4) + wr * 4;        // A fragment chunk-row base
  const int brb = (bcol >> 4) + wc * 4;        // B fragment chunk-row base

  auto loadk = [&](bf16x8* a, bf16x8* b, int kt) {
#pragma unroll
    for (int m = 0; m < 4; ++m)
      a[m] = Lf[((size_t)(arb + m) * 32 + kt * 4) * 16 + lane];
#pragma unroll
    for (int n = 0; n < 4; ++n)
      b[n] = Lf[((size_t)(brb + n) * 32 + kt * 4) * 16 + lane];
  };
  auto mfmak = [&](const bf16x8* a, const bf16x8* b) {
#pragma unroll
    for (int m = 0; m < 4; ++m)
#pragma unroll
      for (int n = 0; n < 4; ++n)
        acc[m][n] = __builtin_amdgcn_mfma_f32_16x16x32_bf16(a[m], b[n], acc[m][n], 0, 0, 0);
  };

  bf16x8 aP[4], bP[4], aQ[4], bQ[4];  // two named sets (static indexing)
  loadk(aP, bP, 0);                   // prologue
#pragma unroll
  for (int kt = 0; kt < 8; kt += 2) { // K = 256 = 8 * 32, ping-pong
    if (kt + 1 < 8) loadk(aQ, bQ, kt + 1);  // prefetch odd step
    mfmak(aP, bP);                          // compute even step
    if (kt + 2 < 8) loadk(aP, bP, kt + 2);  // prefetch next even step
    mfmak(aQ, bQ);                          // compute odd step
  }

  // epilogue (base-2): scale, mask diag, capture targets, exp2, row-direction
  // sums (over tile cols) + column-direction sums (over rows, symmetry)
  float cs[4] = {0.f, 0.f, 0.f, 0.f};
#pragma unroll
  for (int m = 0; m < 4; ++m) {
#pragma unroll
    for (int j = 0; j < 4; ++j) {
      const int gr = brow + wr * 64 + m * 16 + (lane >> 4) * 4 + j;
      const int tgt = (gr < half) ? gr + half : gr - half;
      float rs = 0.f;
#pragma unroll
      for (int n = 0; n < 4; ++n) {
        const int gc = bcol + wc * 64 + n * 16 + (lane & 15);
        const float sv2 = acc[m][n][j] * C2;
        const float ev = (gr == gc) ? 0.f : __builtin_amdgcn_exp2f(sv2);
        if (gc == tgt) {                  // involution: also gr == tgt(gc)
          simTgt[gr] = sv2;
          if (offdiag) simTgt[gc] = sv2;  // sim symmetric
        }
        rs += ev;
        cs[n] += ev;
      }
#pragma unroll
      for (int d = 1; d < 16; d <<= 1) rs += __shfl_xor(rs, d, 64);
      if ((lane & 15) == 0)
        rowPartial[(size_t)(bj * 2 + wc) * N + gr] = rs;
    }
  }
  if (offdiag) {  // column block receives row-sums of the transposed tile
#pragma unroll
    for (int n = 0; n < 4; ++n) {
      float c = cs[n];
      c += __shfl_xor(c, 16, 64);
      c += __shfl_xor(c, 32, 64);
      if ((lane >> 4) == 0)
        rowPartial[(size_t)(bi * 2 + wr) * N + (bcol + wc * 64 + n * 16 + lane)] = c;
    }
  }
}

// ---------------- Kernel 3: row logsumexp-target + deterministic final mean --
__global__ __launch_bounds__(256) void k_rowreduce(const float* __restrict__ rowPartial,
                                                   const float* __restrict__ simTgt,
                                                   float* __restrict__ blockOut,
                                                   unsigned* __restrict__ ticket,
                                                   float* __restrict__ out, int N) {
  const int lane = threadIdx.x & 63;   // row within this block's 64
  const int q = threadIdx.x >> 6;      // partial-chunk 0..3
  const int row = blockIdx.x * 64 + lane;
  float part = 0.f;
#pragma unroll 8
  for (int c = q * 32; c < q * 32 + 32; ++c)
    part += rowPartial[(size_t)c * N + row];
  __shared__ float red[4][64];
  __shared__ int isLast;
  red[q][lane] = part;
  __syncthreads();
  if (threadIdx.x < 64) {
    const float denom = red[0][lane] + red[1][lane] + red[2][lane] + red[3][lane];
    // v_log_f32 = log2; loss = (log2(denom) - sv2) * ln2
    float lossr = (__builtin_amdgcn_logf(denom) - simTgt[row]) * LN2;
#pragma unroll
    for (int d = 32; d; d >>= 1) lossr += __shfl_xor(lossr, d, 64);
    if (threadIdx.x == 0) {
      // device-scope RMW write: coherent across XCDs, deterministic value
      atomicExch(&blockOut[blockIdx.x], lossr);
      isLast = (atomicAdd(ticket, 1u) == gridDim.x - 1);
    }
  }
  __syncthreads();
  if (isLast && threadIdx.x < 64) {
    // coherent read of all 128 block sums via atomic RMW (+0.0f), fixed order
    float v = atomicAdd(&blockOut[threadIdx.x], 0.0f) +
              atomicAdd(&blockOut[64 + threadIdx.x], 0.0f);
#pragma unroll
    for (int d = 32; d; d >>= 1) v += __shfl_xor(v, d, 64);
    if (threadIdx.x == 0) out[0] = v / (float)N;
  }
}

extern "C" void kernel_launch(void* const* d_in, const int* in_sizes, int n_in,
                              void* d_out, int out_size, void* d_ws, size_t ws_size,
                              hipStream_t stream) {
  const float* ei = (const float*)d_in[0];
  const float* ej = (const float*)d_in[1];
  const int B = in_sizes[0] / D_DIM;  // 4096
  const int N = 2 * B;                // 8192

  char* ws = (char*)d_ws;
  unsigned short* R = (unsigned short*)ws;                                   // N*256*2 = 4MB (L layout)
  float* rowPartial = (float*)(ws + (size_t)N * D_DIM * 2);                  // 128*N*4 = 4MB
  float* simTgt     = (float*)(ws + (size_t)N * D_DIM * 2 + (size_t)128 * N * 4);  // N*4
  float* blockOut   = (float*)((char*)simTgt + (size_t)N * 4);               // 128*4
  unsigned* ticket  = (unsigned*)((char*)blockOut + 128 * 4);                // 4B

  k_normalize<<<N / 16, 256, 0, stream>>>(ei, ej, R, ticket, B);
  const int T = N / 128;
  k_simgemm<<<T * (T + 1) / 2, 256, 0, stream>>>(R, rowPartial, simTgt, N);
  k_rowreduce<<<N / 64, 256, 0, stream>>>(rowPartial, simTgt, blockOut, ticket,
                                          (float*)d_out, N);
}

// Round 10
// 51.845 us; speedup vs baseline: 1.3247x; 1.3247x over previous
//
#include <hip/hip_runtime.h>

typedef int i32x4 __attribute__((ext_vector_type(4)));
typedef int i32x8 __attribute__((ext_vector_type(8)));
typedef float f32x4 __attribute__((ext_vector_type(4)));

#define D_DIM 256
// base-2 scale: sv2 = acc * (1/T) * log2(e) = acc * 2 * 1.442695...
#define C2 2.88539008f
#define LN2 0.69314718f

// LDS chunk swizzle (16B units, 16 chunks per 256B fp8 row):
//   slot = chunk ^ ((r&7)<<1) ^ ((r>>3)&1)   (involution)
__device__ __forceinline__ int swz(int r) { return ((r & 7) << 1) ^ ((r >> 3) & 1); }

// ---------------- Kernel 1: L2-normalize -> fp8 e4m3 R[N][256] (linear) -----
// wave = 4 rows x 16 lanes; lane kq owns k [kq*16, kq*16+16).
__global__ __launch_bounds__(256) void k_normalize(const float* __restrict__ ei,
                                                   const float* __restrict__ ej,
                                                   unsigned char* __restrict__ R,
                                                   unsigned* __restrict__ ticket,
                                                   int B) {
  if (blockIdx.x == 0 && threadIdx.x == 0) *ticket = 0u;  // per-call reset
  const int w = threadIdx.x >> 6, lane = threadIdx.x & 63;
  const int row = blockIdx.x * 16 + w * 4 + (lane >> 4);
  const int kq = lane & 15;
  const float* src = (row < B) ? (ei + (size_t)row * D_DIM)
                               : (ej + (size_t)(row - B) * D_DIM);
  const float4* s4 = (const float4*)src + kq * 4;
  float4 v0 = s4[0], v1 = s4[1], v2 = s4[2], v3 = s4[3];
  float ss = v0.x*v0.x + v0.y*v0.y + v0.z*v0.z + v0.w*v0.w
           + v1.x*v1.x + v1.y*v1.y + v1.z*v1.z + v1.w*v1.w
           + v2.x*v2.x + v2.y*v2.y + v2.z*v2.z + v2.w*v2.w
           + v3.x*v3.x + v3.y*v3.y + v3.z*v3.z + v3.w*v3.w;
#pragma unroll
  for (int d = 1; d < 16; d <<= 1) ss += __shfl_xor(ss, d, 64);  // 16-group
  const float s = 1.0f / fmaxf(sqrtf(ss), 1e-12f);
  // pack 16 floats -> 16 fp8 e4m3 bytes (RNE+sat via v_cvt_pk_fp8_f32)
  int q0 = __builtin_amdgcn_cvt_pk_fp8_f32(v0.x*s, v0.y*s, 0, 0);
  q0     = __builtin_amdgcn_cvt_pk_fp8_f32(v0.z*s, v0.w*s, q0, 1);
  int q1 = __builtin_amdgcn_cvt_pk_fp8_f32(v1.x*s, v1.y*s, 0, 0);
  q1     = __builtin_amdgcn_cvt_pk_fp8_f32(v1.z*s, v1.w*s, q1, 1);
  int q2 = __builtin_amdgcn_cvt_pk_fp8_f32(v2.x*s, v2.y*s, 0, 0);
  q2     = __builtin_amdgcn_cvt_pk_fp8_f32(v2.z*s, v2.w*s, q2, 1);
  int q3 = __builtin_amdgcn_cvt_pk_fp8_f32(v3.x*s, v3.y*s, 0, 0);
  q3     = __builtin_amdgcn_cvt_pk_fp8_f32(v3.z*s, v3.w*s, q3, 1);
  i32x4 o = {q0, q1, q2, q3};
  ((i32x4*)R)[(size_t)row * 16 + kq] = o;  // linear: row*256B + kq*16B
}

// ---------------- Kernel 2: symmetric fused sim GEMM + exp partials ---------
// Upper-triangular 128x128 tiles (bi <= bj); off-diag tiles feed both row and
// column blocks (sim symmetric). fp8 MX-scaled MFMA (16x16x128, scales=2^0
// identity) -> 2 MFMA per output frag. SINGLE-STAGE full-K LDS: A panel 32KB
// + B panel 32KB staged once via global_load_lds (swizzled source), ONE
// barrier, then pure compute. 2 blocks/CU; staging of one block overlaps
// compute of its CU-sibling. No K-loop lockstep at all.
__global__ __launch_bounds__(256, 2) void k_simgemm(const unsigned char* __restrict__ R,
                                                    float* __restrict__ rowPartial,
                                                    float* __restrict__ simTgt,
                                                    int N) {
  __shared__ char lds[64 * 1024];  // A panel 32KB | B panel 32KB
  const int tid = threadIdx.x;
  const int w = tid >> 6, lane = tid & 63;
  const int wr = w >> 1, wc = w & 1;
  const int half = N >> 1;

  // decode linear block id -> upper-triangular (bi, bj), bi <= bj
  const int T = N / 128;  // 64
  const int t = blockIdx.x;
  int bi = (int)(((float)(2 * T + 1) -
                  sqrtf((float)((2 * T + 1) * (2 * T + 1) - 8 * t))) * 0.5f);
  while (bi > 0 && t < bi * (2 * T - bi + 1) / 2) --bi;
  while (t >= (bi + 1) * (2 * T - bi) / 2) ++bi;
  const int bj = bi + (t - bi * (2 * T - bi + 1) / 2);
  const int brow = bi * 128, bcol = bj * 128;
  const bool offdiag = (bi != bj);

  // ---- stage both fp8 panels, swizzled source -> linear LDS dest ----------
#pragma unroll
  for (int i = 0; i < 16; ++i) {
    const int cid = i * 256 + tid;          // 16B-chunk id, 0..4095
    const int panel = cid >> 11;            // 0 = A rows, 1 = B cols
    const int pc = cid & 2047;
    const int r = pc >> 4, cs = pc & 15;
    const int c = cs ^ swz(r);              // inverse swizzle on source
    const unsigned char* g = R + (size_t)((panel ? bcol : brow) + r) * 256 + c * 16;
    __builtin_amdgcn_global_load_lds(
        (const __attribute__((address_space(1))) void*)g,
        (__attribute__((address_space(3))) void*)(lds + (size_t)cid * 16), 16, 0, 0);
  }
  __syncthreads();  // drains vmcnt; the only barrier in this kernel

  f32x4 zero4 = {0.f, 0.f, 0.f, 0.f};
  f32x4 acc[4][4];
#pragma unroll
  for (int m = 0; m < 4; ++m)
#pragma unroll
    for (int n = 0; n < 4; ++n) acc[m][n] = zero4;

  const char* ldsA = lds;
  const char* ldsB = lds + 32 * 1024;
  // frag (rl, ks): lane holds 32 k-bytes at granule g = ks*4 + (lane>>4);
  // 16B slots s_lo = (2g)^swz(rl), s_hi = s_lo^1 (XOR linearity).
  auto loadfrag = [&](const char* base, int rl, int ks) -> i32x8 {
    const int g = ks * 4 + (lane >> 4);
    const int s_lo = (2 * g) ^ swz(rl);
    i32x4 lo = *(const i32x4*)(base + rl * 256 + s_lo * 16);
    i32x4 hi = *(const i32x4*)(base + rl * 256 + (s_lo ^ 1) * 16);
    i32x8 f = {lo[0], lo[1], lo[2], lo[3], hi[0], hi[1], hi[2], hi[3]};
    return f;
  };

#pragma unroll
  for (int ks = 0; ks < 2; ++ks) {  // K = 256 = 2 * 128
    i32x8 a[4], b[4];
#pragma unroll
    for (int m = 0; m < 4; ++m) a[m] = loadfrag(ldsA, wr * 64 + m * 16 + (lane & 15), ks);
#pragma unroll
    for (int n = 0; n < 4; ++n) b[n] = loadfrag(ldsB, wc * 64 + n * 16 + (lane & 15), ks);
#pragma unroll
    for (int m = 0; m < 4; ++m)
#pragma unroll
      for (int n = 0; n < 4; ++n)
        acc[m][n] = __builtin_amdgcn_mfma_scale_f32_16x16x128_f8f6f4(
            a[m], b[n], acc[m][n], 0 /*fp8*/, 0 /*fp8*/,
            0, 0x7F7F7F7F /*scaleA=2^0*/, 0, 0x7F7F7F7F /*scaleB=2^0*/);
  }

  // epilogue (base-2): scale, mask diag, capture targets, exp2, row-direction
  // sums (over tile cols) + column-direction sums (over rows, symmetry)
  float cs4[4] = {0.f, 0.f, 0.f, 0.f};
#pragma unroll
  for (int m = 0; m < 4; ++m) {
#pragma unroll
    for (int j = 0; j < 4; ++j) {
      const int gr = brow + wr * 64 + m * 16 + (lane >> 4) * 4 + j;
      const int tgt = (gr < half) ? gr + half : gr - half;
      float rs = 0.f;
#pragma unroll
      for (int n = 0; n < 4; ++n) {
        const int gc = bcol + wc * 64 + n * 16 + (lane & 15);
        const float sv2 = acc[m][n][j] * C2;
        const float ev = (gr == gc) ? 0.f : __builtin_amdgcn_exp2f(sv2);
        if (gc == tgt) {                  // involution: also gr == tgt(gc)
          simTgt[gr] = sv2;
          if (offdiag) simTgt[gc] = sv2;  // sim symmetric
        }
        rs += ev;
        cs4[n] += ev;
      }
#pragma unroll
      for (int d = 1; d < 16; d <<= 1) rs += __shfl_xor(rs, d, 64);
      if ((lane & 15) == 0)
        rowPartial[(size_t)(bj * 2 + wc) * N + gr] = rs;
    }
  }
  if (offdiag) {  // column block receives row-sums of the transposed tile
#pragma unroll
    for (int n = 0; n < 4; ++n) {
      float c = cs4[n];
      c += __shfl_xor(c, 16, 64);
      c += __shfl_xor(c, 32, 64);
      if ((lane >> 4) == 0)
        rowPartial[(size_t)(bi * 2 + wr) * N + (bcol + wc * 64 + n * 16 + lane)] = c;
    }
  }
}

// ---------------- Kernel 3: row logsumexp-target + deterministic final mean --
__global__ __launch_bounds__(256) void k_rowreduce(const float* __restrict__ rowPartial,
                                                   const float* __restrict__ simTgt,
                                                   float* __restrict__ blockOut,
                                                   unsigned* __restrict__ ticket,
                                                   float* __restrict__ out, int N) {
  const int lane = threadIdx.x & 63;   // row within this block's 64
  const int q = threadIdx.x >> 6;      // partial-chunk 0..3
  const int row = blockIdx.x * 64 + lane;
  float part = 0.f;
#pragma unroll 8
  for (int c = q * 32; c < q * 32 + 32; ++c)
    part += rowPartial[(size_t)c * N + row];
  __shared__ float red[4][64];
  __shared__ int isLast;
  red[q][lane] = part;
  __syncthreads();
  if (threadIdx.x < 64) {
    const float denom = red[0][lane] + red[1][lane] + red[2][lane] + red[3][lane];
    // v_log_f32 = log2; loss = (log2(denom) - sv2) * ln2
    float lossr = (__builtin_amdgcn_logf(denom) - simTgt[row]) * LN2;
#pragma unroll
    for (int d = 32; d; d >>= 1) lossr += __shfl_xor(lossr, d, 64);
    if (threadIdx.x == 0) {
      // device-scope RMW write: coherent across XCDs, deterministic value
      atomicExch(&blockOut[blockIdx.x], lossr);
      isLast = (atomicAdd(ticket, 1u) == gridDim.x - 1);
    }
  }
  __syncthreads();
  if (isLast && threadIdx.x < 64) {
    // coherent read of all 128 block sums via atomic RMW (+0.0f), fixed order
    float v = atomicAdd(&blockOut[threadIdx.x], 0.0f) +
              atomicAdd(&blockOut[64 + threadIdx.x], 0.0f);
#pragma unroll
    for (int d = 32; d; d >>= 1) v += __shfl_xor(v, d, 64);
    if (threadIdx.x == 0) out[0] = v / (float)N;
  }
}

extern "C" void kernel_launch(void* const* d_in, const int* in_sizes, int n_in,
                              void* d_out, int out_size, void* d_ws, size_t ws_size,
                              hipStream_t stream) {
  const float* ei = (const float*)d_in[0];
  const float* ej = (const float*)d_in[1];
  const int B = in_sizes[0] / D_DIM;  // 4096
  const int N = 2 * B;                // 8192

  char* ws = (char*)d_ws;
  unsigned char* R = (unsigned char*)ws;                                     // N*256 = 2MB (fp8)
  float* rowPartial = (float*)(ws + (size_t)N * D_DIM);                      // 128*N*4 = 4MB
  float* simTgt     = (float*)(ws + (size_t)N * D_DIM + (size_t)128 * N * 4);  // N*4
  float* blockOut   = (float*)((char*)simTgt + (size_t)N * 4);               // 128*4
  unsigned* ticket  = (unsigned*)((char*)blockOut + 128 * 4);                // 4B

  k_normalize<<<N / 16, 256, 0, stream>>>(ei, ej, R, ticket, B);
  const int T = N / 128;
  k_simgemm<<<T * (T + 1) / 2, 256, 0, stream>>>(R, rowPartial, simTgt, N);
  k_rowreduce<<<N / 64, 256, 0, stream>>>(rowPartial, simTgt, blockOut, ticket,
                                          (float*)d_out, N);
}